// Round 8
// baseline (282.854 us; speedup 1.0000x reference)
//
#include <hip/hip_runtime.h>
#include <hip/hip_bf16.h>

#define NNODES 50000
#define NEDGES 800000
#define DD 128
#define SCAN_B 196   // ceil(50000/256)
#define WPITCH 129   // dwords per W row in LDS (odd -> bank hop 1)
#define NPART 8      // dst partitions (one per XCD)
#define PSIZE 6250   // nodes per partition
#define N8 ((size_t)NNODES * 8)  // u32s per feature slice

typedef unsigned int u32;
typedef unsigned short u16;
typedef short bf16x8 __attribute__((ext_vector_type(8)));
typedef float f32x4 __attribute__((ext_vector_type(4)));

union U4B8 {
    uint4 u;
    bf16x8 b;
};

__device__ __forceinline__ u32 f2b(float f) {
    u32 u = __float_as_uint(f);
    u32 rounding = 0x7fffu + ((u >> 16) & 1u);
    return (u + rounding) >> 16;
}

// ---------------------------------------------------------------------------
// setup_k: (a) W pack -> wb[o][kpair], (b) deg zero, (c) x -> bf16 packed,
// feature-SLICED layout: xb[s*N8 + node*8 + j], slice s = 16 features.
// ---------------------------------------------------------------------------
__global__ __launch_bounds__(256) void setup_k(
    const float* __restrict__ x, const float* __restrict__ Wl,
    const float* __restrict__ Wr, u32* __restrict__ wb,
    u32* __restrict__ xb, u32* __restrict__ deg) {
    int b = blockIdx.x, tid = threadIdx.x;
    if (b < 64) {
        int idx = b * 256 + tid;  // < 16384
        int o = idx >> 7, c = idx & 127, k0 = 2 * c;
        const float* src = (k0 < DD) ? (Wl + o * DD + k0) : (Wr + o * DD + (k0 - DD));
        wb[idx] = f2b(src[0]) | (f2b(src[1]) << 16);
    } else if (b < 260) {
        int i = (b - 64) * 256 + tid;
        if (i < NNODES) deg[i] = 0u;
    } else {
        int i = (b - 260) * 256 + tid;  // < 3,200,000 exactly
        int node = i >> 6, c = i & 63;
        float2 v = ((const float2*)x)[i];  // contiguous read
        int s = c >> 3, j = c & 7;
        xb[(size_t)s * N8 + (size_t)node * 8 + j] = f2b(v.x) | (f2b(v.y) << 16);
    }
}

// ---------------------------------------------------------------------------
// CSR build, dst-partitioned (blockIdx&7 -> XCD-local counter/csr ranges).
// ---------------------------------------------------------------------------
__global__ __launch_bounds__(256) void hist_part_k(
    const int* __restrict__ ei, u32* __restrict__ deg) {
    u32 part = blockIdx.x & (NPART - 1);
    u32 e = (blockIdx.x >> 3) * 256u + threadIdx.x;
    if (e >= NEDGES) return;
    int dst = ei[NEDGES + e];
    if ((u32)(dst - part * PSIZE) < (u32)PSIZE)
        atomicAdd(deg + dst, 1u);
}

__global__ __launch_bounds__(256) void scan1_k(
    const u32* __restrict__ deg, u32* __restrict__ part) {
    __shared__ u32 s[256];
    int i = blockIdx.x * 256 + threadIdx.x;
    int t = threadIdx.x;
    s[t] = (i < NNODES) ? deg[i] : 0u;
    __syncthreads();
    for (int off = 128; off > 0; off >>= 1) {
        if (t < off) s[t] += s[t + off];
        __syncthreads();
    }
    if (t == 0) part[blockIdx.x] = s[0];
}

__global__ __launch_bounds__(256) void scan2_k(u32* __restrict__ part) {
    __shared__ u32 s[256];
    int t = threadIdx.x;
    u32 v = (t < SCAN_B) ? part[t] : 0u;
    s[t] = v;
    __syncthreads();
    for (int off = 1; off < 256; off <<= 1) {
        u32 a = (t >= off) ? s[t - off] : 0u;
        __syncthreads();
        s[t] += a;
        __syncthreads();
    }
    if (t < SCAN_B) part[t] = s[t] - v;  // exclusive
}

__global__ __launch_bounds__(256) void scan3_k(
    const u32* __restrict__ deg, const u32* __restrict__ part,
    u32* __restrict__ row_ptr, u32* __restrict__ cursor) {
    __shared__ u32 s[256];
    int i = blockIdx.x * 256 + threadIdx.x;
    int t = threadIdx.x;
    u32 v = (i < NNODES) ? deg[i] : 0u;
    s[t] = v;
    __syncthreads();
    for (int off = 1; off < 256; off <<= 1) {
        u32 a = (t >= off) ? s[t - off] : 0u;
        __syncthreads();
        s[t] += a;
        __syncthreads();
    }
    if (i < NNODES) {
        u32 e = part[blockIdx.x] + s[t] - v;
        row_ptr[i] = e;
        cursor[i] = e;
    }
}

__global__ __launch_bounds__(256) void fill_part_k(
    const int* __restrict__ ei, u32* __restrict__ cursor,
    u32* __restrict__ csr) {
    u32 part = blockIdx.x & (NPART - 1);
    u32 e = (blockIdx.x >> 3) * 256u + threadIdx.x;
    if (e >= NEDGES) return;
    int dst = ei[NEDGES + e];
    if ((u32)(dst - part * PSIZE) < (u32)PSIZE) {
        u32 pos = atomicAdd(cursor + dst, 1u);
        csr[pos] = (u32)ei[e];
    }
}

// ---------------------------------------------------------------------------
// Sliced gather-mean: block -> (node group, slice); slice = blockIdx&7 pins
// a 1.6 MB xb slice per XCD (fits 4 MiB L2 -> kills the 109 MB L2-miss
// traffic of the full-row gather). Wave = 1 node: 8 lanes per neighbor row,
// 8 rows per load instruction; shfl_xor(8,16,32) reduction; lanes 0-7 write
// the 32 B aggb slice.
// ---------------------------------------------------------------------------
__global__ __launch_bounds__(256) void gather_slice_k(
    const u32* __restrict__ xb, const u32* __restrict__ csr,
    const u32* __restrict__ row_ptr, const u32* __restrict__ deg,
    u32* __restrict__ aggb) {
    const u32 slice = blockIdx.x & 7u;
    const u32 node = (blockIdx.x >> 3) * 4u + (threadIdx.x >> 6);  // 12500*4=50000
    const u32 lane = threadIdx.x & 63u;
    const u32 sub = lane >> 3;  // neighbor sub-row 0..7
    const u32 j = lane & 7u;    // u32 within slice
    const u32 d = deg[node];
    const u32 beg = row_ptr[node], end = beg + d;
    const u32* xs = xb + (size_t)slice * N8;
    float a0 = 0.f, a1 = 0.f;
    for (u32 i0 = beg; i0 < end; i0 += 8u) {
        u32 idx = i0 + sub;
        bool valid = idx < end;
        u32 row = csr[valid ? idx : (end - 1u)];
        u32 v = xs[(size_t)row * 8 + j];
        if (!valid) v = 0u;
        a0 += __uint_as_float(v << 16);
        a1 += __uint_as_float(v & 0xffff0000u);
    }
    a0 += __shfl_xor(a0, 8, 64);
    a1 += __shfl_xor(a1, 8, 64);
    a0 += __shfl_xor(a0, 16, 64);
    a1 += __shfl_xor(a1, 16, 64);
    a0 += __shfl_xor(a0, 32, 64);
    a1 += __shfl_xor(a1, 32, 64);
    if (lane < 8) {
        float inv = 1.0f / fmaxf((float)d, 1.0f);
        aggb[(size_t)slice * N8 + (size_t)node * 8 + lane] =
            f2b(a0 * inv) | (f2b(a1 * inv) << 16);
    }
}

// ---------------------------------------------------------------------------
// MFMA fused dual-GEMM: out = relu([aggb|xb] @ [Wl;Wr]^T + b), A in sliced
// layout (uint4 loads stay within one 8-u32 slice block since off in {0,4}).
// ---------------------------------------------------------------------------
__global__ __launch_bounds__(256) void mfma_fused_k(
    const u32* __restrict__ aggb, const u32* __restrict__ xb,
    const u32* __restrict__ wb, const float* __restrict__ bl,
    float* __restrict__ out) {
    __shared__ u32 w_lds[DD * WPITCH];
    __shared__ float sbias[DD];
    const int tid = threadIdx.x;
    for (int r = tid >> 5; r < DD; r += 8) {
        int c = (tid & 31) * 4;
        uint4 v = *(const uint4*)&wb[r * DD + c];
        *(uint4*)&w_lds[r * WPITCH + c] = v;
    }
    if (tid < DD) sbias[tid] = bl[tid];
    __syncthreads();

    const int wave = tid >> 6, lane = tid & 63;
    const int m = lane & 15, quad = lane >> 4;
    const int row0 = blockIdx.x * 128 + wave * 32;

    f32x4 acc[2][8];
#pragma unroll
    for (int t = 0; t < 2; ++t)
#pragma unroll
        for (int nt = 0; nt < 8; ++nt) acc[t][nt] = (f32x4){0.f, 0.f, 0.f, 0.f};

    for (int ks = 0; ks < 8; ++ks) {
        const u32* A = (ks < 4) ? aggb : xb;
        const int kc = (ks & 3) * 16 + quad * 4;  // u32 index in 64-u32 row
        const int s = kc >> 3, off = kc & 7;      // slice, offset (0 or 4)
        U4B8 af[2];
#pragma unroll
        for (int t = 0; t < 2; ++t) {
            int r = row0 + t * 16 + m;
            r = r < NNODES ? r : NNODES - 1;
            af[t].u = *(const uint4*)&A[(size_t)s * N8 + (size_t)r * 8 + off];
        }
#pragma unroll
        for (int nt = 0; nt < 8; ++nt) {
            U4B8 bf;
            bf.u = *(const uint4*)&w_lds[(nt * 16 + m) * WPITCH + ks * 16 + quad * 4];
            acc[0][nt] = __builtin_amdgcn_mfma_f32_16x16x32_bf16(
                af[0].b, bf.b, acc[0][nt], 0, 0, 0);
            acc[1][nt] = __builtin_amdgcn_mfma_f32_16x16x32_bf16(
                af[1].b, bf.b, acc[1][nt], 0, 0, 0);
        }
    }
#pragma unroll
    for (int t = 0; t < 2; ++t) {
#pragma unroll
        for (int nt = 0; nt < 8; ++nt) {
            int col = nt * 16 + m;
            float b = sbias[col];
#pragma unroll
            for (int r = 0; r < 4; ++r) {
                int row = row0 + t * 16 + quad * 4 + r;
                if (row < NNODES)
                    out[(size_t)row * DD + col] = fmaxf(acc[t][nt][r] + b, 0.f);
            }
        }
    }
}

// ---------------------------------------------------------------------------
// Small-ws fallback (R2 path)
// ---------------------------------------------------------------------------
__global__ __launch_bounds__(256) void scatter_k(
    const float* __restrict__ x, const int* __restrict__ ei,
    float* __restrict__ agg, u32* __restrict__ deg) {
    u32 gid = blockIdx.x * 256u + threadIdx.x;
    u32 edge = gid >> 6;
    u32 lane = gid & 63u;
    if (edge >= NEDGES) return;
    int src = ei[edge];
    int dst = ei[NEDGES + edge];
    float2 v = ((const float2*)(x + (size_t)src * DD))[lane];
    float* p = agg + (size_t)dst * DD + lane * 2u;
    unsafeAtomicAdd(p, v.x);
    unsafeAtomicAdd(p + 1, v.y);
    if (lane == 0) atomicAdd(deg + dst, 1u);
}

__global__ __launch_bounds__(256) void mean_k(
    float* __restrict__ agg, const u32* __restrict__ deg) {
    u32 gid = blockIdx.x * 256u + threadIdx.x;
    u32 node = gid >> 6;
    u32 lane = gid & 63u;
    if (node >= NNODES) return;
    float inv = 1.0f / fmaxf((float)deg[node], 1.0f);
    float2* p = (float2*)(agg + (size_t)node * DD) + lane;
    float2 v = *p;
    *p = make_float2(v.x * inv, v.y * inv);
}

__global__ __launch_bounds__(256) void lin_l_k(
    float* __restrict__ agg,
    const float* __restrict__ Wl, const float* __restrict__ bl) {
    __shared__ u32 WT[DD * 65];
    __shared__ float rows[4 * DD];
    __shared__ float sbias[DD];
    const int tid = threadIdx.x;
    {
        u16* WTs = (u16*)WT;
        for (int i = tid; i < DD * DD; i += 256) {
            int o = i >> 7, k = i & 127;
            WTs[k * 130 + o] = (u16)f2b(Wl[i]);
        }
        if (tid < DD) sbias[tid] = bl[tid];
    }
    __syncthreads();
    const int h = tid & 63;
    const int nl = tid >> 6;
    for (int base = blockIdx.x * 4; base < NNODES; base += gridDim.x * 4) {
        ((float2*)rows)[tid] =
            ((const float2*)(agg + (size_t)(base + (tid >> 6)) * DD))[tid & 63];
        __syncthreads();
        float acc0 = sbias[2 * h], acc1 = sbias[2 * h + 1];
#pragma unroll
        for (int k = 0; k < DD; ++k) {
            float a = rows[nl * DD + k];
            u32 w2 = WT[k * 65 + h];
            acc0 = fmaf(a, __uint_as_float(w2 << 16), acc0);
            acc1 = fmaf(a, __uint_as_float(w2 & 0xffff0000u), acc1);
        }
        __syncthreads();
        ((float2*)(agg + (size_t)(base + nl) * DD))[h] = make_float2(acc0, acc1);
    }
}

__global__ __launch_bounds__(256) void lin_r_k(
    float* __restrict__ io, const float* __restrict__ x,
    const float* __restrict__ Wr) {
    __shared__ u32 WT[DD * 65];
    __shared__ float rows[4 * DD];
    const int tid = threadIdx.x;
    {
        u16* WTs = (u16*)WT;
        for (int i = tid; i < DD * DD; i += 256) {
            int o = i >> 7, k = i & 127;
            WTs[k * 130 + o] = (u16)f2b(Wr[i]);
        }
    }
    __syncthreads();
    const int h = tid & 63;
    const int nl = tid >> 6;
    for (int base = blockIdx.x * 4; base < NNODES; base += gridDim.x * 4) {
        ((float2*)rows)[tid] =
            ((const float2*)(x + (size_t)(base + (tid >> 6)) * DD))[tid & 63];
        __syncthreads();
        float2 t2 = ((const float2*)(io + (size_t)(base + nl) * DD))[h];
        float acc0 = t2.x, acc1 = t2.y;
#pragma unroll
        for (int k = 0; k < DD; ++k) {
            float a = rows[nl * DD + k];
            u32 w2 = WT[k * 65 + h];
            acc0 = fmaf(a, __uint_as_float(w2 << 16), acc0);
            acc1 = fmaf(a, __uint_as_float(w2 & 0xffff0000u), acc1);
        }
        acc0 = fmaxf(acc0, 0.f);
        acc1 = fmaxf(acc1, 0.f);
        __syncthreads();
        ((float2*)(io + (size_t)(base + nl) * DD))[h] = make_float2(acc0, acc1);
    }
}

extern "C" void kernel_launch(void* const* d_in, const int* in_sizes, int n_in,
                              void* d_out, int out_size, void* d_ws, size_t ws_size,
                              hipStream_t stream) {
    const float* x  = (const float*)d_in[0];
    const int*   ei = (const int*)d_in[1];
    const float* Wl = (const float*)d_in[2];
    const float* bl = (const float*)d_in[3];
    const float* Wr = (const float*)d_in[4];

    // ws layout: deg | row_ptr | cursor | csr | part | wb | xb | aggb
    u32* deg     = (u32*)d_ws;
    u32* row_ptr = deg + NNODES;
    u32* cursor  = row_ptr + NNODES;
    u32* csr     = cursor + NNODES;
    u32* part    = csr + NEDGES;
    u32* wb      = part + 256;
    u32* xb      = wb + 16384;
    u32* aggb    = xb + N8 * 8;
    const size_t need =
        ((size_t)(3 * NNODES + NEDGES + 256 + 16384) + (size_t)NNODES * 128) * 4;

    if (ws_size >= need) {
        setup_k<<<12760, 256, 0, stream>>>(x, Wl, Wr, wb, xb, deg);
        hist_part_k<<<3125 * NPART, 256, 0, stream>>>(ei, deg);
        scan1_k<<<SCAN_B, 256, 0, stream>>>(deg, part);
        scan2_k<<<1, 256, 0, stream>>>(part);
        scan3_k<<<SCAN_B, 256, 0, stream>>>(deg, part, row_ptr, cursor);
        fill_part_k<<<3125 * NPART, 256, 0, stream>>>(ei, cursor, csr);
        gather_slice_k<<<12500 * 8, 256, 0, stream>>>(xb, csr, row_ptr, deg, aggb);
        mfma_fused_k<<<(NNODES + 127) / 128, 256, 0, stream>>>(
            aggb, xb, wb, bl, (float*)d_out);
    } else {
        float* agg = (float*)d_out;
        hipMemsetAsync(d_out, 0, (size_t)NNODES * DD * sizeof(float), stream);
        hipMemsetAsync(d_ws, 0, (size_t)NNODES * sizeof(u32), stream);
        scatter_k<<<(NEDGES * 64) / 256, 256, 0, stream>>>(x, ei, agg, deg);
        mean_k<<<(NNODES * 64 + 255) / 256, 256, 0, stream>>>(agg, deg);
        lin_l_k<<<1024, 256, 0, stream>>>(agg, Wl, bl);
        lin_r_k<<<1024, 256, 0, stream>>>(agg, x, Wr);
    }
}